// Round 1
// baseline (481.059 us; speedup 1.0000x reference)
//
#include <hip/hip_runtime.h>
#include <math.h>
#include <stdint.h>

#define B_ 8
#define S_ 2048
#define E_ 1024
#define D_ 64
#define LDK 72   // LDS row stride in bf16 elems: 64 + 8 pad (keeps 16B alignment, breaks bank aliasing)

typedef __attribute__((ext_vector_type(8))) short bf16x8;
typedef __attribute__((ext_vector_type(4))) float f32x4;

static __device__ __forceinline__ unsigned short f2bf(float f) {
    union { float f; unsigned u; } v; v.f = f;
    unsigned r = v.u + 0x7FFFu + ((v.u >> 16) & 1u);   // RNE
    return (unsigned short)(r >> 16);
}

// ---------------------------------------------------------------------------
// K1: projections. out[m][d] = sum_e X[m][e] * W[d][e]  (bf16 MFMA, fp32 acc)
// A-frag: lane holds X[m = 16*wv + (lane&15)][k = ks*32 + (lane>>4)*8 + j]
// B-frag: lane holds W[n = 16*nt + (lane&15)][k = ...]  (W is [d][e] row-major: already B-layout)
// C/D   : row = (lane>>4)*4 + reg, col = lane&15   (verified m89/m91)
// which==2 (V) writes transposed VT[b][d][s] so PV's B operand is [n=d][k=t]-contiguous.
// ---------------------------------------------------------------------------
__global__ __launch_bounds__(256) void proj_kernel(
    const float* __restrict__ Xq, const float* __restrict__ Xk, const float* __restrict__ Xv,
    const float* __restrict__ Wq, const float* __restrict__ Wk, const float* __restrict__ Wv,
    unsigned short* __restrict__ Qb, unsigned short* __restrict__ Kb,
    unsigned short* __restrict__ VTb)
{
    __shared__ unsigned short Xs[64 * LDK];
    __shared__ unsigned short Ws[64 * LDK];

    const int which = blockIdx.y;
    const float* __restrict__ X = (which == 0) ? Xq : (which == 1) ? Xk : Xv;
    const float* __restrict__ W = (which == 0) ? Wq : (which == 1) ? Wk : Wv;

    const int tid  = threadIdx.x;
    const int lane = tid & 63;
    const int wv   = tid >> 6;      // 0..3 m-subtile
    const int quad = lane >> 4;
    const int l15  = lane & 15;
    const int rowBase = blockIdx.x * 64;

    f32x4 acc[4];
    #pragma unroll
    for (int i = 0; i < 4; i++) { f32x4 z = {0.f, 0.f, 0.f, 0.f}; acc[i] = z; }

    for (int e0 = 0; e0 < E_; e0 += 64) {
        // stage X tile 64x64 fp32 -> bf16 LDS
        #pragma unroll
        for (int i = 0; i < 4; i++) {
            int idx = tid + i * 256;          // float4 units, 0..1023
            int r = idx >> 4, c = idx & 15;
            float4 v = *(const float4*)(X + (size_t)(rowBase + r) * E_ + e0 + c * 4);
            unsigned short* p = &Xs[r * LDK + c * 4];
            p[0] = f2bf(v.x); p[1] = f2bf(v.y); p[2] = f2bf(v.z); p[3] = f2bf(v.w);
        }
        // stage W tile 64x64 fp32 -> bf16 LDS (all 64 d-rows, e-slice)
        #pragma unroll
        for (int i = 0; i < 4; i++) {
            int idx = tid + i * 256;
            int r = idx >> 4, c = idx & 15;
            float4 v = *(const float4*)(W + (size_t)r * E_ + e0 + c * 4);
            unsigned short* p = &Ws[r * LDK + c * 4];
            p[0] = f2bf(v.x); p[1] = f2bf(v.y); p[2] = f2bf(v.z); p[3] = f2bf(v.w);
        }
        __syncthreads();
        #pragma unroll
        for (int ks = 0; ks < 2; ks++) {
            bf16x8 af = *(const bf16x8*)&Xs[(16 * wv + l15) * LDK + ks * 32 + quad * 8];
            #pragma unroll
            for (int nt = 0; nt < 4; nt++) {
                bf16x8 bf = *(const bf16x8*)&Ws[(16 * nt + l15) * LDK + ks * 32 + quad * 8];
                acc[nt] = __builtin_amdgcn_mfma_f32_16x16x32_bf16(af, bf, acc[nt], 0, 0, 0);
            }
        }
        __syncthreads();
    }

    if (which < 2) {
        unsigned short* O = (which == 0) ? Qb : Kb;
        #pragma unroll
        for (int nt = 0; nt < 4; nt++)
            #pragma unroll
            for (int reg = 0; reg < 4; reg++) {
                int m = rowBase + 16 * wv + quad * 4 + reg;
                int d = 16 * nt + l15;
                O[(size_t)m * D_ + d] = f2bf(acc[nt][reg]);
            }
    } else {
        #pragma unroll
        for (int nt = 0; nt < 4; nt++)
            #pragma unroll
            for (int reg = 0; reg < 4; reg++) {
                int m = rowBase + 16 * wv + quad * 4 + reg;
                int b = m >> 11, sl = m & 2047;
                int d = 16 * nt + l15;
                VTb[((size_t)b * D_ + d) * S_ + sl] = f2bf(acc[nt][reg]);
            }
    }
}

// ---------------------------------------------------------------------------
// K2: logits[b][s][t] = 0.125 * dot(Q[b][s], K[b][t]); mask -> -inf; fp32 into Sc.
// batch = bid & 7 so blocks of one batch land on one XCD (L2 holds Q[b]+K[b] = 512 KB).
// ---------------------------------------------------------------------------
__global__ __launch_bounds__(256) void qk_kernel(
    const unsigned short* __restrict__ Qb, const unsigned short* __restrict__ Kb,
    const unsigned char* __restrict__ mask, float* __restrict__ Sc)
{
    __shared__ unsigned short Qs[64 * LDK];
    __shared__ unsigned short Ks[64 * LDK];

    const int tid = threadIdx.x, lane = tid & 63, wv = tid >> 6;
    const int quad = lane >> 4, l15 = lane & 15;
    const int bid = blockIdx.x;
    const int b  = bid & 7;
    const int t2 = bid >> 3;
    const int sB = (t2 >> 5) * 64;
    const int tB = (t2 & 31) * 64;

    const uint4* Qg = (const uint4*)(Qb + ((size_t)b * S_ + sB) * D_);
    const uint4* Kg = (const uint4*)(Kb + ((size_t)b * S_ + tB) * D_);
    #pragma unroll
    for (int i = 0; i < 2; i++) {
        int idx = tid + i * 256;          // uint4 units: 8 per 64-bf16 row
        int r = idx >> 3, c = idx & 7;
        *(uint4*)&Qs[r * LDK + c * 8] = Qg[r * 8 + c];
        *(uint4*)&Ks[r * LDK + c * 8] = Kg[r * 8 + c];
    }
    __syncthreads();

    f32x4 acc[4];
    #pragma unroll
    for (int i = 0; i < 4; i++) { f32x4 z = {0.f, 0.f, 0.f, 0.f}; acc[i] = z; }

    #pragma unroll
    for (int ks = 0; ks < 2; ks++) {
        bf16x8 af = *(const bf16x8*)&Qs[(16 * wv + l15) * LDK + ks * 32 + quad * 8];
        #pragma unroll
        for (int nt = 0; nt < 4; nt++) {
            bf16x8 bf = *(const bf16x8*)&Ks[(16 * nt + l15) * LDK + ks * 32 + quad * 8];
            acc[nt] = __builtin_amdgcn_mfma_f32_16x16x32_bf16(af, bf, acc[nt], 0, 0, 0);
        }
    }

    #pragma unroll
    for (int nt = 0; nt < 4; nt++)
        #pragma unroll
        for (int reg = 0; reg < 4; reg++) {
            int s = sB + 16 * wv + quad * 4 + reg;
            int t = tB + 16 * nt + l15;
            size_t off = ((size_t)b * S_ + s) * (size_t)S_ + t;
            float lg = acc[nt][reg] * 0.125f;
            if (mask[off]) lg = -INFINITY;
            Sc[off] = lg;
        }
}

// ---------------------------------------------------------------------------
// K3: per-row max and 1/sum(exp). One wave per row, row kept in registers.
// ---------------------------------------------------------------------------
__global__ __launch_bounds__(256) void rowstat_kernel(
    const float* __restrict__ Sc, float* __restrict__ rmax, float* __restrict__ rinv)
{
    const int lane = threadIdx.x & 63;
    const int row  = blockIdx.x * 4 + (threadIdx.x >> 6);
    const float4* L4 = (const float4*)(Sc + (size_t)row * S_);   // 512 float4 per row
    float4 vv[8];
    float mx = -INFINITY;
    #pragma unroll
    for (int i = 0; i < 8; i++) {
        vv[i] = L4[lane + i * 64];
        mx = fmaxf(mx, fmaxf(fmaxf(vv[i].x, vv[i].y), fmaxf(vv[i].z, vv[i].w)));
    }
    #pragma unroll
    for (int off = 32; off > 0; off >>= 1) mx = fmaxf(mx, __shfl_xor(mx, off));
    float sm = 0.f;
    #pragma unroll
    for (int i = 0; i < 8; i++)
        sm += __expf(vv[i].x - mx) + __expf(vv[i].y - mx) +
              __expf(vv[i].z - mx) + __expf(vv[i].w - mx);
    #pragma unroll
    for (int off = 32; off > 0; off >>= 1) sm += __shfl_xor(sm, off);
    if (lane == 0) { rmax[row] = mx; rinv[row] = 1.0f / sm; }
}

// ---------------------------------------------------------------------------
// K4: probs = exp(logit - max) * inv  -> written fp32 to Sc (output 1), bf16 to LDS;
//     attention = P @ V via MFMA with VT (B-operand [d][t]-contiguous). 1024 thr = 16 waves
//     = 16 (msub,nsub) MFMA tiles of the 64s x 64d block output.
// ---------------------------------------------------------------------------
__global__ __launch_bounds__(1024) void pv_kernel(
    float* __restrict__ Sc, const unsigned short* __restrict__ VTb,
    const float* __restrict__ rmax, const float* __restrict__ rinv,
    float* __restrict__ Att)
{
    __shared__ unsigned short Ps[64 * LDK];
    __shared__ unsigned short Vs[64 * LDK];
    __shared__ float rm[64];
    __shared__ float ri[64];

    const int tid = threadIdx.x, lane = tid & 63, wv = tid >> 6;   // wv 0..15
    const int quad = lane >> 4, l15 = lane & 15;
    const int bid = blockIdx.x;
    const int b = bid & 7, sB = (bid >> 3) * 64;
    const int msub = wv >> 2, nsub = wv & 3;

    if (tid < 64) {
        int row = b * S_ + sB + tid;
        rm[tid] = rmax[row];
        ri[tid] = rinv[row];
    }
    __syncthreads();

    f32x4 acc = {0.f, 0.f, 0.f, 0.f};
    const int pr = tid >> 4, pc = tid & 15;   // P stage: 64 rows x 16 float4-cols
    const int vd = tid >> 3, vc = tid & 7;    // V stage: 64 d-rows x 8 uint4-cols (tid<512)

    for (int t0 = 0; t0 < S_; t0 += 64) {
        size_t off = ((size_t)b * S_ + sB + pr) * (size_t)S_ + t0 + pc * 4;
        float4 v = *(const float4*)(Sc + off);
        float m = rm[pr], s = ri[pr];
        v.x = __expf(v.x - m) * s;
        v.y = __expf(v.y - m) * s;
        v.z = __expf(v.z - m) * s;
        v.w = __expf(v.w - m) * s;
        *(float4*)(Sc + off) = v;             // final normalized score output (fp32)
        unsigned short* p = &Ps[pr * LDK + pc * 4];
        p[0] = f2bf(v.x); p[1] = f2bf(v.y); p[2] = f2bf(v.z); p[3] = f2bf(v.w);
        if (tid < 512) {
            *(uint4*)&Vs[vd * LDK + vc * 8] =
                *(const uint4*)(VTb + ((size_t)b * D_ + vd) * S_ + t0 + vc * 8);
        }
        __syncthreads();
        #pragma unroll
        for (int ks = 0; ks < 2; ks++) {
            bf16x8 af = *(const bf16x8*)&Ps[(16 * msub + l15) * LDK + ks * 32 + quad * 8];
            bf16x8 bf = *(const bf16x8*)&Vs[(16 * nsub + l15) * LDK + ks * 32 + quad * 8];
            acc = __builtin_amdgcn_mfma_f32_16x16x32_bf16(af, bf, acc, 0, 0, 0);
        }
        __syncthreads();
    }
    #pragma unroll
    for (int reg = 0; reg < 4; reg++) {
        int s = sB + 16 * msub + quad * 4 + reg;
        int d = 16 * nsub + l15;
        Att[((size_t)b * S_ + s) * D_ + d] = acc[reg];
    }
}

// ---------------------------------------------------------------------------
extern "C" void kernel_launch(void* const* d_in, const int* in_sizes, int n_in,
                              void* d_out, int out_size, void* d_ws, size_t ws_size,
                              hipStream_t stream)
{
    const float* q  = (const float*)d_in[0];
    const float* k  = (const float*)d_in[1];
    const float* v  = (const float*)d_in[2];
    const unsigned char* mask = (const unsigned char*)d_in[3];  // jnp bool -> 1 byte
    const float* wq = (const float*)d_in[4];
    const float* wk = (const float*)d_in[5];
    const float* wv = (const float*)d_in[6];

    float* out = (float*)d_out;
    float* Att = out;                                  // [B,S,D] = 1,048,576 f32
    float* Sc  = out + (size_t)B_ * S_ * D_;           // [B,S,S] = 33,554,432 f32

    // workspace: Qb(2MB) Kb(2MB) VT(2MB) rmax(64KB) rinv(64KB)  ~6.4 MB
    unsigned short* Qb = (unsigned short*)d_ws;
    unsigned short* Kb = Qb + (size_t)B_ * S_ * D_;
    unsigned short* VT = Kb + (size_t)B_ * S_ * D_;
    float* rmax = (float*)(VT + (size_t)B_ * S_ * D_);
    float* rinv = rmax + (size_t)B_ * S_;

    hipLaunchKernelGGL(proj_kernel, dim3(256, 3), dim3(256), 0, stream,
                       q, k, v, wq, wk, wv, Qb, Kb, VT);
    hipLaunchKernelGGL(qk_kernel, dim3(8192), dim3(256), 0, stream, Qb, Kb, mask, Sc);
    hipLaunchKernelGGL(rowstat_kernel, dim3(4096), dim3(256), 0, stream, Sc, rmax, rinv);
    hipLaunchKernelGGL(pv_kernel, dim3(256), dim3(1024), 0, stream, Sc, VT, rmax, rinv, Att);
}

// Round 2
// 432.982 us; speedup vs baseline: 1.1110x; 1.1110x over previous
//
#include <hip/hip_runtime.h>
#include <math.h>
#include <stdint.h>

#define B_ 8
#define S_ 2048
#define E_ 1024
#define D_ 64
#define LDK 72   // LDS row stride in bf16 elems (64 + 8 pad)

typedef __attribute__((ext_vector_type(8))) short bf16x8;
typedef __attribute__((ext_vector_type(4))) float f32x4;

static __device__ __forceinline__ unsigned short f2bf(float f) {
    union { float f; unsigned u; } v; v.f = f;
    unsigned r = v.u + 0x7FFFu + ((v.u >> 16) & 1u);   // RNE
    return (unsigned short)(r >> 16);
}

// ---------------------------------------------------------------------------
// K0: convert W (fp32 [3][64][1024]) -> bf16, same layout. Tiny; makes proj's
// B-operand loadable as ready-made bf16 fragments (L2-resident, 384 KB).
// ---------------------------------------------------------------------------
__global__ __launch_bounds__(256) void wconv_kernel(
    const float* __restrict__ Wq, const float* __restrict__ Wk,
    const float* __restrict__ Wv, unsigned short* __restrict__ Wb)
{
    const int which = blockIdx.x >> 6;                 // 64 blocks per matrix
    const float* W = (which == 0) ? Wq : (which == 1) ? Wk : Wv;
    const int i = ((blockIdx.x & 63) * 256 + threadIdx.x) * 4;
    float4 v = *(const float4*)(W + i);
    ushort4 o;
    o.x = f2bf(v.x); o.y = f2bf(v.y); o.z = f2bf(v.z); o.w = f2bf(v.w);
    *(ushort4*)(Wb + (size_t)which * 65536 + i) = o;
}

// ---------------------------------------------------------------------------
// K1: projections, NO LDS / NO barriers. Each wave owns 16 output rows.
// A-frag: lane reads X[m0+l15][k..k+7] fp32 straight from global (16 rows x
// 128B segments), converts in-register. B-frag: bf16 W from global (L2 hit).
// Index math identical to the round-1 verified kernel.
// which==2 (V) emits transposed VT[b][d][s] for PV's B operand.
// ---------------------------------------------------------------------------
__global__ __launch_bounds__(256) void proj_kernel(
    const float* __restrict__ Xq, const float* __restrict__ Xk,
    const float* __restrict__ Xv, const unsigned short* __restrict__ Wb,
    unsigned short* __restrict__ Qb, unsigned short* __restrict__ Kb,
    unsigned short* __restrict__ VTb)
{
    const int which = blockIdx.y;
    const float* __restrict__ X = (which == 0) ? Xq : (which == 1) ? Xk : Xv;
    const unsigned short* __restrict__ W = Wb + (size_t)which * 65536;

    const int tid  = threadIdx.x;
    const int lane = tid & 63;
    const int wv   = tid >> 6;
    const int quad = lane >> 4;
    const int l15  = lane & 15;
    const int m    = blockIdx.x * 64 + wv * 16 + l15;   // A-frag row for this lane

    f32x4 acc[4];
    #pragma unroll
    for (int i = 0; i < 4; i++) { f32x4 z = {0.f, 0.f, 0.f, 0.f}; acc[i] = z; }

    const float* __restrict__ xrow = X + (size_t)m * E_;

    #pragma unroll 2
    for (int e0 = 0; e0 < E_; e0 += 64) {
        #pragma unroll
        for (int ks = 0; ks < 2; ks++) {
            const int k = e0 + ks * 32 + quad * 8;
            float4 a0 = *(const float4*)(xrow + k);
            float4 a1 = *(const float4*)(xrow + k + 4);
            union { unsigned short u[8]; bf16x8 v; } af;
            af.u[0] = f2bf(a0.x); af.u[1] = f2bf(a0.y);
            af.u[2] = f2bf(a0.z); af.u[3] = f2bf(a0.w);
            af.u[4] = f2bf(a1.x); af.u[5] = f2bf(a1.y);
            af.u[6] = f2bf(a1.z); af.u[7] = f2bf(a1.w);
            #pragma unroll
            for (int nt = 0; nt < 4; nt++) {
                bf16x8 bf = *(const bf16x8*)(W + (size_t)(16 * nt + l15) * E_ + k);
                acc[nt] = __builtin_amdgcn_mfma_f32_16x16x32_bf16(af.v, bf, acc[nt], 0, 0, 0);
            }
        }
    }

    // C/D layout (verified): row = quad*4 + reg (within wave's 16), col = 16*nt + l15
    if (which < 2) {
        unsigned short* O = (which == 0) ? Qb : Kb;
        #pragma unroll
        for (int nt = 0; nt < 4; nt++)
            #pragma unroll
            for (int reg = 0; reg < 4; reg++) {
                int mg = blockIdx.x * 64 + wv * 16 + quad * 4 + reg;
                int d  = 16 * nt + l15;
                O[(size_t)mg * D_ + d] = f2bf(acc[nt][reg]);
            }
    } else {
        #pragma unroll
        for (int nt = 0; nt < 4; nt++)
            #pragma unroll
            for (int reg = 0; reg < 4; reg++) {
                int mg = blockIdx.x * 64 + wv * 16 + quad * 4 + reg;
                int b  = mg >> 11, sl = mg & 2047;
                int d  = 16 * nt + l15;
                VTb[((size_t)b * D_ + d) * S_ + sl] = f2bf(acc[nt][reg]);
            }
    }
}

// ---------------------------------------------------------------------------
// K2: fused attention. Per block: 32 query rows of one batch. 8 waves =
// (msub 0..1) x (nsub 0..3) 16x16 MFMA tiles of the 32x64 (s x t / s x d) outputs.
// Pass A: recompute QK^T tiles, accumulate per-row sum(exp(logit)) (max-free
// softmax: logits bf16-bounded, exact math). Pass B: recompute logits
// (bit-identical MFMA), p = exp*inv -> write Sc (only mandatory 128 MB) and
// bf16 Ps -> LDS -> A-frag for PV MFMA with VT global B-frags.
// Mask bytes read once, bit-packed into 8 KB LDS, reused in pass B.
// ---------------------------------------------------------------------------
__global__ __launch_bounds__(512) void attn_kernel(
    const unsigned short* __restrict__ Qb, const unsigned short* __restrict__ Kb,
    const unsigned short* __restrict__ VTb, const unsigned char* __restrict__ mask,
    float* __restrict__ Sc, float* __restrict__ Att)
{
    __shared__ unsigned short Qs[32 * LDK];
    __shared__ unsigned short Ks[64 * LDK];
    __shared__ unsigned short Ps[32 * LDK];
    __shared__ unsigned char  Mb[32 * 32 * 8];   // [it][sl][8B] bit-packed mask
    __shared__ float Sums[4 * 32];
    __shared__ float Inv[32];

    const int tid  = threadIdx.x;
    const int lane = tid & 63;
    const int wv   = tid >> 6;        // 0..7
    const int quad = lane >> 4, l15 = lane & 15;
    const int msub = wv >> 2, nsub = wv & 3;
    const int b  = blockIdx.x & 7;            // batch -> XCD affinity
    const int sB = (blockIdx.x >> 3) * 32;

    // stage Q tile 32x64 bf16 (once)
    if (tid < 256) {
        int r = tid >> 3, c = tid & 7;
        *(uint4*)&Qs[r * LDK + c * 8] =
            *(const uint4*)(Qb + ((size_t)(b * S_ + sB + r)) * D_ + c * 8);
    }

    const int kr = tid >> 3, kc = tid & 7;    // K staging map (64 rows x 8 uint4)

    // ---------------- pass A: row sums of exp(logit) ----------------
    float sum_[4] = {0.f, 0.f, 0.f, 0.f};
    for (int it = 0; it < 32; it++) {
        const int t0 = it * 64;
        *(uint4*)&Ks[kr * LDK + kc * 8] =
            *(const uint4*)(Kb + ((size_t)(b * S_ + t0 + kr)) * D_ + kc * 8);
        if (tid < 256) {   // pack 32x64 mask bytes -> bits
            int r = tid >> 3, c8 = tid & 7;
            uint2 u = *(const uint2*)(mask + ((size_t)(b * S_ + sB + r)) * S_ + t0 + c8 * 8);
            unsigned n0 = (u.x | (u.x >> 7) | (u.x >> 14) | (u.x >> 21)) & 0xF;
            unsigned n1 = (u.y | (u.y >> 7) | (u.y >> 14) | (u.y >> 21)) & 0xF;
            Mb[(it * 32 + r) * 8 + c8] = (unsigned char)(n0 | (n1 << 4));
        }
        __syncthreads();
        f32x4 a = {0.f, 0.f, 0.f, 0.f};
        #pragma unroll
        for (int ks = 0; ks < 2; ks++) {
            bf16x8 af = *(const bf16x8*)&Qs[(16 * msub + l15) * LDK + ks * 32 + quad * 8];
            bf16x8 bf = *(const bf16x8*)&Ks[(16 * nsub + l15) * LDK + ks * 32 + quad * 8];
            a = __builtin_amdgcn_mfma_f32_16x16x32_bf16(af, bf, a, 0, 0, 0);
        }
        #pragma unroll
        for (int reg = 0; reg < 4; reg++) {
            int sl = 16 * msub + quad * 4 + reg;
            uint2 w = *(const uint2*)&Mb[(it * 32 + sl) * 8];
            unsigned wd = (nsub < 2) ? w.x : w.y;
            int bit = (wd >> (16 * (nsub & 1) + l15)) & 1;
            float e = bit ? 0.f : __expf(a[reg] * 0.125f);
            sum_[reg] += e;
        }
        __syncthreads();   // protect Ks restage
    }
    // reduce over the 16 lanes sharing a quad (t-subset cols)
    #pragma unroll
    for (int off = 1; off < 16; off <<= 1)
        #pragma unroll
        for (int reg = 0; reg < 4; reg++)
            sum_[reg] += __shfl_xor(sum_[reg], off);
    if (l15 == 0) {
        #pragma unroll
        for (int reg = 0; reg < 4; reg++)
            Sums[nsub * 32 + 16 * msub + quad * 4 + reg] = sum_[reg];
    }
    __syncthreads();
    if (tid < 32) {
        float s = Sums[tid] + Sums[32 + tid] + Sums[64 + tid] + Sums[96 + tid];
        Inv[tid] = 1.0f / s;
    }
    __syncthreads();

    // ---------------- pass B: emit probs + PV ----------------
    f32x4 acc = {0.f, 0.f, 0.f, 0.f};
    for (int it = 0; it < 32; it++) {
        const int t0 = it * 64;
        *(uint4*)&Ks[kr * LDK + kc * 8] =
            *(const uint4*)(Kb + ((size_t)(b * S_ + t0 + kr)) * D_ + kc * 8);
        __syncthreads();
        f32x4 a = {0.f, 0.f, 0.f, 0.f};
        #pragma unroll
        for (int ks = 0; ks < 2; ks++) {
            bf16x8 af = *(const bf16x8*)&Qs[(16 * msub + l15) * LDK + ks * 32 + quad * 8];
            bf16x8 bf = *(const bf16x8*)&Ks[(16 * nsub + l15) * LDK + ks * 32 + quad * 8];
            a = __builtin_amdgcn_mfma_f32_16x16x32_bf16(af, bf, a, 0, 0, 0);
        }
        #pragma unroll
        for (int reg = 0; reg < 4; reg++) {
            int sl = 16 * msub + quad * 4 + reg;
            uint2 w = *(const uint2*)&Mb[(it * 32 + sl) * 8];
            unsigned wd = (nsub < 2) ? w.x : w.y;
            int bit = (wd >> (16 * (nsub & 1) + l15)) & 1;
            float p = bit ? 0.f : __expf(a[reg] * 0.125f) * Inv[sl];
            Sc[((size_t)(b * S_ + sB + sl)) * S_ + t0 + 16 * nsub + l15] = p;
            Ps[sl * LDK + 16 * nsub + l15] = f2bf(p);
        }
        __syncthreads();
        #pragma unroll
        for (int ks = 0; ks < 2; ks++) {
            bf16x8 af = *(const bf16x8*)&Ps[(16 * msub + l15) * LDK + ks * 32 + quad * 8];
            bf16x8 bf = *(const bf16x8*)(VTb +
                ((size_t)(b * D_ + 16 * nsub + l15)) * S_ + t0 + ks * 32 + quad * 8);
            acc = __builtin_amdgcn_mfma_f32_16x16x32_bf16(af, bf, acc, 0, 0, 0);
        }
        // next-iter top barrier orders Ks restage vs this iter's reads
    }
    #pragma unroll
    for (int reg = 0; reg < 4; reg++) {
        int sl = 16 * msub + quad * 4 + reg;
        Att[((size_t)(b * S_ + sB + sl)) * D_ + 16 * nsub + l15] = acc[reg];
    }
}

// ---------------------------------------------------------------------------
extern "C" void kernel_launch(void* const* d_in, const int* in_sizes, int n_in,
                              void* d_out, int out_size, void* d_ws, size_t ws_size,
                              hipStream_t stream)
{
    const float* q  = (const float*)d_in[0];
    const float* k  = (const float*)d_in[1];
    const float* v  = (const float*)d_in[2];
    const unsigned char* mask = (const unsigned char*)d_in[3];
    const float* wq = (const float*)d_in[4];
    const float* wk = (const float*)d_in[5];
    const float* wv = (const float*)d_in[6];

    float* out = (float*)d_out;
    float* Att = out;                                  // [B,S,D]
    float* Sc  = out + (size_t)B_ * S_ * D_;           // [B,S,S]

    // ws: Wb (384 KB) | Qb (2MB) | Kb (2MB) | VT (2MB)
    unsigned short* Wb = (unsigned short*)d_ws;
    unsigned short* Qb = Wb + (size_t)3 * 65536;
    unsigned short* Kb = Qb + (size_t)B_ * S_ * D_;
    unsigned short* VT = Kb + (size_t)B_ * S_ * D_;

    hipLaunchKernelGGL(wconv_kernel, dim3(192), dim3(256), 0, stream, wq, wk, wv, Wb);
    hipLaunchKernelGGL(proj_kernel, dim3(256, 3), dim3(256), 0, stream,
                       q, k, v, Wb, Qb, Kb, VT);
    hipLaunchKernelGGL(attn_kernel, dim3(512), dim3(512), 0, stream,
                       Qb, Kb, VT, mask, Sc, Att);
}